// Round 1
// baseline (527.359 us; speedup 1.0000x reference)
//
#include <hip/hip_runtime.h>

typedef _Float16 f16;
typedef f16 f16x8 __attribute__((ext_vector_type(8)));
typedef float f32x4 __attribute__((ext_vector_type(4)));

#define MT 64
#define NSTEP 30

__device__ __forceinline__ float fast_sigmoid(float x) {
    float e = __expf(-x);
    return __builtin_amdgcn_rcpf(1.0f + e);
}
__device__ __forceinline__ float fast_tanh(float x) {
    float e = __expf(2.0f * x);
    return 1.0f - 2.0f * __builtin_amdgcn_rcpf(1.0f + e);
}

// One WG = 64 batch rows, 8 waves. Wave w owns hidden units [16w,16w+16)
// (all 4 gates). W_hh/W_ih fragments live in registers across all 30 steps.
// h tile cycles through double-buffered, XOR-swizzled LDS (f16).
// MFMA k-map (both operands): k = kf*32 + g*8 + j  (g = lane>>4, j = slot).
// D-layout (m89-verified): row = (lane>>4)*4 + reg, col = lane&15.
__global__ __launch_bounds__(512) void mdlstm_kernel(
    const float* __restrict__ lor,   // last_obs_rel (B,2)
    const float* __restrict__ h0,    // (B,128)
    const float* __restrict__ c0,    // (B,128)
    const float* __restrict__ W_ih,  // (512,16)
    const float* __restrict__ W_hh,  // (512,128)
    const float* __restrict__ b_ih, const float* __restrict__ b_hh,
    const float* __restrict__ W_emb, // (16,12)
    const float* __restrict__ b_emb, // (16)
    const float* __restrict__ W_pos, // (12,128)
    const float* __restrict__ b_pos, // (12)
    const float* __restrict__ W_conf,// (6,128)
    const float* __restrict__ b_conf,// (6)
    float* __restrict__ out, int batch)
{
    __shared__ f16 h_lds[2 * MT * 128];
    __shared__ f16 x_lds[MT * 16];
    __shared__ f16 rel_lds[MT * 16];

    const int tid = threadIdx.x;
    const int wv  = tid >> 6;    // wave 0..7
    const int ln  = tid & 63;
    const int g   = ln >> 4;     // lane group 0..3
    const int q   = ln & 15;
    const int b0  = blockIdx.x * MT;
    if (b0 >= batch) return;

    // ---- persistent weight fragments ----
    f16x8 whh[4][4];             // [gate][kf]
    #pragma unroll
    for (int g4 = 0; g4 < 4; ++g4) {
        const int col = g4 * 128 + wv * 16 + q;
        #pragma unroll
        for (int kf = 0; kf < 4; ++kf) {
            const float* p = W_hh + col * 128 + kf * 32 + g * 8;
            f16x8 v;
            #pragma unroll
            for (int j = 0; j < 8; ++j) v[j] = (f16)p[j];
            whh[g4][kf] = v;
        }
    }
    f16x8 wih[4];                // K=16 padded to 32 (g>=2 -> 0)
    #pragma unroll
    for (int g4 = 0; g4 < 4; ++g4) {
        const int col = g4 * 128 + wv * 16 + q;
        f16x8 v = {};
        if (g < 2) {
            const float* p = W_ih + col * 16 + g * 8;
            #pragma unroll
            for (int j = 0; j < 8; ++j) v[j] = (f16)p[j];
        }
        wih[g4] = v;
    }
    float bg[4];
    #pragma unroll
    for (int g4 = 0; g4 < 4; ++g4) {
        const int col = g4 * 128 + wv * 16 + q;
        bg[g4] = b_ih[col] + b_hh[col];
    }
    f16x8 wpos[4];               // B[k][n] = (n<12) ? W_pos[n][k] : 0
    #pragma unroll
    for (int kf = 0; kf < 4; ++kf) {
        f16x8 v = {};
        if (q < 12) {
            const float* p = W_pos + q * 128 + kf * 32 + g * 8;
            #pragma unroll
            for (int j = 0; j < 8; ++j) v[j] = (f16)p[j];
        }
        wpos[kf] = v;
    }
    const float bpos = (q < 12) ? b_pos[q] : 0.0f;
    f16x8 wemb = {};             // B[k][n] = (k<12) ? W_emb[n][k] : 0
    #pragma unroll
    for (int j = 0; j < 8; ++j) {
        const int k = g * 8 + j;
        if (k < 12) wemb[j] = (f16)W_emb[q * 12 + k];
    }
    const float bemb = b_emb[q];

    // ---- c state in registers (D-layout) ----
    f32x4 c_st[4];
    #pragma unroll
    for (int mt = 0; mt < 4; ++mt)
        #pragma unroll
        for (int r = 0; r < 4; ++r)
            c_st[mt][r] = c0[(b0 + mt * 16 + g * 4 + r) * 128 + wv * 16 + q];

    // ---- stage h0 -> h_lds buf0 (f16, chunk-XOR swizzle) ----
    {
        const int row = tid >> 3;    // 0..63
        const int seg = tid & 7;     // 16 floats
        const float* p = h0 + (b0 + row) * 128 + seg * 16;
        #pragma unroll
        for (int half = 0; half < 2; ++half) {
            f16x8 v;
            #pragma unroll
            for (int j = 0; j < 8; ++j) v[j] = (f16)p[half * 8 + j];
            const int chunk = seg * 2 + half;
            *(f16x8*)&h_lds[row * 128 + ((chunk ^ (row & 7)) << 3)] = v;
        }
    }

    // ---- x0 = leaky(rel0 @ W_emb^T + b_emb): waves 0-3, mt = wv ----
    if (wv < 4) {
        const int mt = wv;
        const int m  = mt * 16 + q;
        const float lx = lor[(b0 + m) * 2 + 0];
        const float ly = lor[(b0 + m) * 2 + 1];
        f16x8 rf = {};
        #pragma unroll
        for (int j = 0; j < 8; ++j) {
            const int k = g * 8 + j;
            if (k < 12) rf[j] = (f16)((j & 1) ? ly : lx);
        }
        f32x4 xacc = {bemb, bemb, bemb, bemb};
        xacc = __builtin_amdgcn_mfma_f32_16x16x32_f16(rf, wemb, xacc, 0, 0, 0);
        #pragma unroll
        for (int r = 0; r < 4; ++r) {
            float xv = xacc[r];
            xv = fmaxf(xv, 0.01f * xv);               // leaky_relu
            x_lds[(mt * 16 + g * 4 + r) * 16 + q] = (f16)xv;
        }
    }

    // ---- conf = softmax(h0 @ W_conf^T + b_conf): once, VALU ----
    {
        const int e  = tid >> 3;
        const int p8 = tid & 7;
        const float* hp = h0 + (b0 + e) * 128 + p8 * 16;
        float pc[6];
        #pragma unroll
        for (int md = 0; md < 6; ++md) {
            const float* wc = W_conf + md * 128 + p8 * 16;
            float s = 0.f;
            #pragma unroll
            for (int i = 0; i < 16; ++i) s += hp[i] * wc[i];
            pc[md] = s;
        }
        #pragma unroll
        for (int md = 0; md < 6; ++md) {
            pc[md] += __shfl_down(pc[md], 4, 8);
            pc[md] += __shfl_down(pc[md], 2, 8);
            pc[md] += __shfl_down(pc[md], 1, 8);
        }
        if (p8 == 0) {
            float mx = -1e30f;
            #pragma unroll
            for (int md = 0; md < 6; ++md) { pc[md] += b_conf[md]; mx = fmaxf(mx, pc[md]); }
            float s = 0.f;
            #pragma unroll
            for (int md = 0; md < 6; ++md) { pc[md] = __expf(pc[md] - mx); s += pc[md]; }
            const float rs = __builtin_amdgcn_rcpf(s);
            float* cp = out + batch * 360 + (b0 + e) * 6;
            #pragma unroll
            for (int md = 0; md < 6; ++md) cp[md] = pc[md] * rs;
        }
    }

    __syncthreads();

    int buf = 0;
    for (int t = 0; t < NSTEP; ++t) {
        const int hbase_r = buf * (MT * 128);
        const int hbase_w = (buf ^ 1) * (MT * 128);
        #pragma unroll
        for (int mt = 0; mt < 4; ++mt) {
            const int row = mt * 16 + q;
            f16x8 hf[4];
            #pragma unroll
            for (int kf = 0; kf < 4; ++kf)
                hf[kf] = *(const f16x8*)&h_lds[hbase_r + row * 128 + (((4 * kf + g) ^ (row & 7)) << 3)];
            f16x8 xf = {};
            if (g < 2) xf = *(const f16x8*)&x_lds[row * 16 + g * 8];
            f32x4 acc[4];
            #pragma unroll
            for (int g4 = 0; g4 < 4; ++g4) {
                f32x4 a = {bg[g4], bg[g4], bg[g4], bg[g4]};
                #pragma unroll
                for (int kf = 0; kf < 4; ++kf)
                    a = __builtin_amdgcn_mfma_f32_16x16x32_f16(hf[kf], whh[g4][kf], a, 0, 0, 0);
                a = __builtin_amdgcn_mfma_f32_16x16x32_f16(xf, wih[g4], a, 0, 0, 0);
                acc[g4] = a;
            }
            // activations + c/h update; h' -> other buffer (f16, swizzled)
            #pragma unroll
            for (int r = 0; r < 4; ++r) {
                const float iv = fast_sigmoid(acc[0][r]);
                const float fv = fast_sigmoid(acc[1][r]);
                const float gv = fast_tanh(acc[2][r]);
                const float ov = fast_sigmoid(acc[3][r]);
                const float cv = fv * c_st[mt][r] + iv * gv;
                c_st[mt][r] = cv;
                const float hv = ov * fast_tanh(cv);
                const int wrow = mt * 16 + g * 4 + r;
                const int k = wv * 16 + q;
                h_lds[hbase_w + wrow * 128 + (((k >> 3) ^ (wrow & 7)) << 3) + (k & 7)] = (f16)hv;
            }
        }
        __syncthreads();   // h' complete

        if (wv < 4) {      // rel_pos, pred store, x_next  (mt = wv)
            const int mt = wv;
            const int row = mt * 16 + q;
            f16x8 hf[4];
            #pragma unroll
            for (int kf = 0; kf < 4; ++kf)
                hf[kf] = *(const f16x8*)&h_lds[hbase_w + row * 128 + (((4 * kf + g) ^ (row & 7)) << 3)];
            f32x4 racc = {bpos, bpos, bpos, bpos};
            #pragma unroll
            for (int kf = 0; kf < 4; ++kf)
                racc = __builtin_amdgcn_mfma_f32_16x16x32_f16(hf[kf], wpos[kf], racc, 0, 0, 0);
            #pragma unroll
            for (int r = 0; r < 4; ++r) {
                const int m = mt * 16 + g * 4 + r;
                if (q < 12)
                    out[(b0 + m) * 360 + (q >> 1) * 60 + t * 2 + (q & 1)] = racc[r];
                rel_lds[m * 16 + q] = (f16)racc[r];   // cols>=12 write 0 (bpos pad)
            }
            __threadfence_block();                    // same-wave LDS RAW fence
            f16x8 rf = {};
            if (g < 2) rf = *(const f16x8*)&rel_lds[row * 16 + g * 8];
            f32x4 xacc = {bemb, bemb, bemb, bemb};
            xacc = __builtin_amdgcn_mfma_f32_16x16x32_f16(rf, wemb, xacc, 0, 0, 0);
            #pragma unroll
            for (int r = 0; r < 4; ++r) {
                float xv = xacc[r];
                xv = fmaxf(xv, 0.01f * xv);
                x_lds[(mt * 16 + g * 4 + r) * 16 + q] = (f16)xv;
            }
        }
        buf ^= 1;
        __syncthreads();   // x_next / h visible to all for next step
    }
}

extern "C" void kernel_launch(void* const* d_in, const int* in_sizes, int n_in,
                              void* d_out, int out_size, void* d_ws, size_t ws_size,
                              hipStream_t stream) {
    const float* last_obs_rel = (const float*)d_in[1];
    const float* h0     = (const float*)d_in[2];
    const float* c0     = (const float*)d_in[3];
    const float* W_ih   = (const float*)d_in[4];
    const float* W_hh   = (const float*)d_in[5];
    const float* b_ih   = (const float*)d_in[6];
    const float* b_hh   = (const float*)d_in[7];
    const float* W_emb  = (const float*)d_in[8];
    const float* b_emb  = (const float*)d_in[9];
    const float* W_pos  = (const float*)d_in[10];
    const float* b_pos  = (const float*)d_in[11];
    const float* W_conf = (const float*)d_in[12];
    const float* b_conf = (const float*)d_in[13];
    float* out = (float*)d_out;

    const int batch = in_sizes[1] / 2;   // last_obs_rel is (B,2)
    const int grid  = (batch + MT - 1) / MT;
    mdlstm_kernel<<<grid, 512, 0, stream>>>(last_obs_rel, h0, c0, W_ih, W_hh,
                                            b_ih, b_hh, W_emb, b_emb, W_pos,
                                            b_pos, W_conf, b_conf, out, batch);
}

// Round 3
// 461.117 us; speedup vs baseline: 1.1437x; 1.1437x over previous
//
#include <hip/hip_runtime.h>

typedef _Float16 f16;
typedef f16 f16x2 __attribute__((ext_vector_type(2)));
typedef f16 f16x4 __attribute__((ext_vector_type(4)));
typedef f16 f16x8 __attribute__((ext_vector_type(8)));
typedef float f32x4 __attribute__((ext_vector_type(4)));
typedef __fp16 fp16x2_raw __attribute__((ext_vector_type(2)));

#define MT 64
#define NSTEP 30
#define LOG2E 1.4426950408889634f

__device__ __forceinline__ float rcp_f(float x) { return __builtin_amdgcn_rcpf(x); }
__device__ __forceinline__ float exp2_f(float x) {
#if __has_builtin(__builtin_amdgcn_exp2f)
    return __builtin_amdgcn_exp2f(x);
#else
    return __builtin_exp2f(x);
#endif
}
__device__ __forceinline__ f16x2 pk2(float a, float b) {
    fp16x2_raw t = __builtin_amdgcn_cvt_pkrtz(a, b);
    return __builtin_bit_cast(f16x2, t);
}
__device__ __forceinline__ f16x4 pk4(float a, float b, float c, float d) {
    f16x2 lo = pk2(a, b), hi = pk2(c, d);
    f16x4 r; r[0] = lo[0]; r[1] = lo[1]; r[2] = hi[0]; r[3] = hi[1];
    return r;
}

// One WG = 64 batch rows, 8 waves. Wave wv owns hidden units [16wv,16wv+16).
// All GEMMs computed TRANSPOSED: D = W_frag(A) @ h_frag(B) so D is unit-major:
// lane (g,q) holds D[unit 4g+r][batch q] -> 4 consecutive units per batch row
// -> h writeback is one packed ds_write_b64 per mt (was 16 scalar b16).
// LDS h layout: [row 64][k 128] f16, 8B chunks c swizzled c^=4*(row&7)
// (pair-preserving for b128 reads; conflict-free at LDS floor both sides).
// Gate weights/biases pre-scaled by -log2e (i,f,o) / +2log2e (g) so
// activations use v_exp_f32 (2^x) directly; gate bias rides in k-slot 16 of
// the W_ih fragment (B-side supplies constant 1.0 there).
__global__ __launch_bounds__(512) void mdlstm_kernel(
    const float* __restrict__ lor,   // last_obs_rel (B,2)
    const float* __restrict__ h0,    // (B,128)
    const float* __restrict__ c0,    // (B,128)
    const float* __restrict__ W_ih,  // (512,16)
    const float* __restrict__ W_hh,  // (512,128)
    const float* __restrict__ b_ih, const float* __restrict__ b_hh,
    const float* __restrict__ W_emb, // (16,12)
    const float* __restrict__ b_emb, // (16)
    const float* __restrict__ W_pos, // (12,128)
    const float* __restrict__ b_pos, // (12)
    const float* __restrict__ W_conf,// (6,128)
    const float* __restrict__ b_conf,// (6)
    float* __restrict__ out, int batch)
{
    __shared__ f16 h_lds[2 * MT * 128];   // 32 KB, double-buffered
    __shared__ f16 x_lds[MT * 16];        // 2 KB (x^T: [row][emb])
    __shared__ f16 rel_lds[MT * 16];      // 2 KB
    __shared__ f16 wpos_lds[4 * 64 * 8];  // 4 KB: W_pos fragments [kf][lane][8]

    char* hb   = (char*)h_lds;
    char* xb   = (char*)x_lds;
    char* relb = (char*)rel_lds;
    char* wpb  = (char*)wpos_lds;

    const int tid = threadIdx.x;
    const int wv  = tid >> 6;    // wave 0..7
    const int ln  = tid & 63;
    const int g   = ln >> 4;     // lane group 0..3
    const int q   = ln & 15;
    const int b0  = blockIdx.x * MT;
    if (b0 >= batch) return;

    const float gsc[4] = {-LOG2E, -LOG2E, 2.f * LOG2E, -LOG2E};

    // ---- persistent weight fragments (A-operands; same lane-map as B) ----
    f16x8 whh[4][4];             // [gate][kf], pre-scaled
    #pragma unroll
    for (int g4 = 0; g4 < 4; ++g4) {
        const int col = g4 * 128 + wv * 16 + q;
        #pragma unroll
        for (int kf = 0; kf < 4; ++kf) {
            const float* p = W_hh + col * 128 + kf * 32 + g * 8;
            f16x8 v;
            #pragma unroll
            for (int j = 0; j < 8; ++j) v[j] = (f16)(p[j] * gsc[g4]);
            whh[g4][kf] = v;
        }
    }
    f16x8 wih[4];                // K=16 emb + bias in slot k=16 (g==2,j==0)
    #pragma unroll
    for (int g4 = 0; g4 < 4; ++g4) {
        const int col = g4 * 128 + wv * 16 + q;
        f16x8 v = {};
        if (g < 2) {
            const float* p = W_ih + col * 16 + g * 8;
            #pragma unroll
            for (int j = 0; j < 8; ++j) v[j] = (f16)(p[j] * gsc[g4]);
        } else if (g == 2) {
            v[0] = (f16)((b_ih[col] + b_hh[col]) * gsc[g4]);
        }
        wih[g4] = v;
    }
    f16x8 wemb = {};             // A[emb q][traj k], k<12
    #pragma unroll
    for (int j = 0; j < 8; ++j) {
        const int k = g * 8 + j;
        if (k < 12) wemb[j] = (f16)W_emb[q * 12 + k];
    }
    f32x4 bembv, bposv;          // biases now indexed by D-row 4g+r
    #pragma unroll
    for (int r = 0; r < 4; ++r) {
        bembv[r] = b_emb[4 * g + r];
        bposv[r] = (4 * g + r < 12) ? b_pos[4 * g + r] : 0.f;
    }

    // W_pos fragments -> LDS (saves 16 VGPR; tiny per-step read)
    if (wv == 0) {
        #pragma unroll
        for (int kf = 0; kf < 4; ++kf) {
            f16x8 v = {};
            if (q < 12) {
                const float* p = W_pos + q * 128 + kf * 32 + g * 8;
                #pragma unroll
                for (int j = 0; j < 8; ++j) v[j] = (f16)p[j];
            }
            *(f16x8*)(wpb + kf * 1024 + ln * 16) = v;
        }
    }

    // ---- c state in registers: c[16mt+q][16wv+4g+r] ----
    f32x4 c_st[4];
    #pragma unroll
    for (int mt = 0; mt < 4; ++mt)
        c_st[mt] = *(const f32x4*)(c0 + (size_t)(b0 + 16 * mt + q) * 128 + 16 * wv + 4 * g);

    // ---- precomputed LDS byte addresses (loop-invariant) ----
    const int swz = (q & 7) << 5;
    int rdbase[4];
    #pragma unroll
    for (int kf = 0; kf < 4; ++kf) rdbase[kf] = q * 256 + ((kf * 64 + g * 16) ^ swz);
    const int wrb = q * 256 + ((wv * 32 + g * 8) ^ swz);
    const int xrd = q * 32 + g * 16;     // valid g<2
    const int xwr = q * 32 + g * 8;

    float* outp = out + (size_t)(b0 + 16 * wv + q) * 360 + 2 * g * 60; // wv<4,g<3

    // ---- stage h0 -> h_lds buf0 (f16, chunk swizzle) ----
    {
        const int row = tid >> 3, seg = tid & 7;
        const float* p = h0 + (size_t)(b0 + row) * 128 + seg * 16;
        const int rswz = (row & 7) << 5;
        #pragma unroll
        for (int hh = 0; hh < 2; ++hh) {
            f16x8 v;
            #pragma unroll
            for (int j = 0; j < 8; ++j) v[j] = (f16)p[hh * 8 + j];
            const int off = row * 256 + (((seg * 4 + 2 * hh) * 8) ^ rswz);
            *(f16x8*)(hb + off) = v;
        }
    }

    // ---- x0^T = leaky(W_emb @ rel0^T + b_emb): waves 0-3, mt = wv ----
    if (wv < 4) {
        const float2 xy = *(const float2*)(lor + (size_t)(b0 + 16 * wv + q) * 2);
        f16x8 rf = {};
        if (g < 2) {
            #pragma unroll
            for (int j = 0; j < 8; ++j) {
                const int k = g * 8 + j;
                if (k < 12) rf[j] = (f16)((k & 1) ? xy.y : xy.x);
            }
        }
        f32x4 xacc = bembv;
        xacc = __builtin_amdgcn_mfma_f32_16x16x32_f16(wemb, rf, xacc, 0, 0, 0);
        f16x4 xp = pk4(fmaxf(xacc[0], .01f * xacc[0]), fmaxf(xacc[1], .01f * xacc[1]),
                       fmaxf(xacc[2], .01f * xacc[2]), fmaxf(xacc[3], .01f * xacc[3]));
        *(f16x4*)(xb + wv * 512 + xwr) = xp;
    }

    // ---- conf = softmax(h0 @ W_conf^T + b_conf) ----
    {
        const int e  = tid >> 3;
        const int p8 = tid & 7;
        const float* hp = h0 + (size_t)(b0 + e) * 128 + p8 * 16;
        float pc[6];
        #pragma unroll
        for (int md = 0; md < 6; ++md) {
            const float* wc = W_conf + md * 128 + p8 * 16;
            float s = 0.f;
            #pragma unroll
            for (int i = 0; i < 16; ++i) s += hp[i] * wc[i];
            pc[md] = s;
        }
        #pragma unroll
        for (int md = 0; md < 6; ++md) {
            pc[md] += __shfl_down(pc[md], 4, 8);
            pc[md] += __shfl_down(pc[md], 2, 8);
            pc[md] += __shfl_down(pc[md], 1, 8);
        }
        if (p8 == 0) {
            float mx = -1e30f;
            #pragma unroll
            for (int md = 0; md < 6; ++md) { pc[md] += b_conf[md]; mx = fmaxf(mx, pc[md]); }
            float s = 0.f;
            #pragma unroll
            for (int md = 0; md < 6; ++md) { pc[md] = __expf(pc[md] - mx); s += pc[md]; }
            const float rs = rcp_f(s);
            float* cp = out + (size_t)batch * 360 + (size_t)(b0 + e) * 6;
            #pragma unroll
            for (int md = 0; md < 6; ++md) cp[md] = pc[md] * rs;
        }
    }

    __syncthreads();

#define STEP(BR, BW, T_) do {                                                   \
    _Pragma("unroll")                                                           \
    for (int mt = 0; mt < 4; ++mt) {                                            \
        f32x4 a0 = {0,0,0,0}, a1 = {0,0,0,0}, a2 = {0,0,0,0}, a3 = {0,0,0,0};   \
        _Pragma("unroll")                                                       \
        for (int kf = 0; kf < 4; ++kf) {                                        \
            f16x8 hf = *(const f16x8*)(hb + (BR) + mt * 4096 + rdbase[kf]);     \
            a0 = __builtin_amdgcn_mfma_f32_16x16x32_f16(whh[0][kf], hf, a0, 0, 0, 0); \
            a1 = __builtin_amdgcn_mfma_f32_16x16x32_f16(whh[1][kf], hf, a1, 0, 0, 0); \
            a2 = __builtin_amdgcn_mfma_f32_16x16x32_f16(whh[2][kf], hf, a2, 0, 0, 0); \
            a3 = __builtin_amdgcn_mfma_f32_16x16x32_f16(whh[3][kf], hf, a3, 0, 0, 0); \
        }                                                                       \
        {                                                                       \
            f16x8 xf = {};                                                      \
            if (g < 2)       xf = *(const f16x8*)(xb + mt * 512 + xrd);         \
            else if (g == 2) xf[0] = (f16)1.f;                                  \
            a0 = __builtin_amdgcn_mfma_f32_16x16x32_f16(wih[0], xf, a0, 0, 0, 0); \
            a1 = __builtin_amdgcn_mfma_f32_16x16x32_f16(wih[1], xf, a1, 0, 0, 0); \
            a2 = __builtin_amdgcn_mfma_f32_16x16x32_f16(wih[2], xf, a2, 0, 0, 0); \
            a3 = __builtin_amdgcn_mfma_f32_16x16x32_f16(wih[3], xf, a3, 0, 0, 0); \
        }                                                                       \
        f32x4 hv;                                                               \
        _Pragma("unroll")                                                       \
        for (int r = 0; r < 4; ++r) {                                           \
            const float ei = exp2_f(a0[r]);                                     \
            const float ef = exp2_f(a1[r]);                                     \
            const float eg = exp2_f(a2[r]);                                     \
            const float eo = exp2_f(a3[r]);                                     \
            const float sf  = rcp_f(1.f + ef);                                  \
            const float itg = (eg - 1.f) * rcp_f((1.f + ei) * (1.f + eg));      \
            const float cv  = sf * c_st[mt][r] + itg;                           \
            c_st[mt][r] = cv;                                                   \
            const float ec = exp2_f(fminf(cv, 30.f) * (2.f * LOG2E));           \
            hv[r] = (ec - 1.f) * rcp_f((1.f + eo) * (1.f + ec));                \
        }                                                                       \
        *(f16x4*)(hb + (BW) + mt * 4096 + wrb) = pk4(hv[0], hv[1], hv[2], hv[3]); \
    }                                                                           \
    __syncthreads();  /* h(t) ready */                                          \
    if (wv < 4) {                                                               \
        f32x4 racc = bposv;                                                     \
        _Pragma("unroll")                                                       \
        for (int kf = 0; kf < 4; ++kf) {                                        \
            f16x8 wp = *(const f16x8*)(wpb + kf * 1024 + ln * 16);              \
            f16x8 hf = *(const f16x8*)(hb + (BW) + wv * 4096 + rdbase[kf]);     \
            racc = __builtin_amdgcn_mfma_f32_16x16x32_f16(wp, hf, racc, 0, 0, 0); \
        }                                                                       \
        if (g < 3) {                                                            \
            float2 s0 = {racc[0], racc[1]};                                     \
            float2 s1 = {racc[2], racc[3]};                                     \
            float* pp = outp + 2 * (T_);                                        \
            *(float2*)pp = s0;                                                  \
            *(float2*)(pp + 60) = s1;                                           \
        }                                                                       \
        *(f16x4*)(relb + wv * 512 + xwr) = pk4(racc[0], racc[1], racc[2], racc[3]); \
        __threadfence_block();                                                  \
        f16x8 rf = {};                                                          \
        if (g < 2) rf = *(const f16x8*)(relb + wv * 512 + xrd);                 \
        f32x4 xacc = bembv;                                                     \
        xacc = __builtin_amdgcn_mfma_f32_16x16x32_f16(wemb, rf, xacc, 0, 0, 0); \
        f16x4 xp = pk4(fmaxf(xacc[0], .01f * xacc[0]), fmaxf(xacc[1], .01f * xacc[1]), \
                       fmaxf(xacc[2], .01f * xacc[2]), fmaxf(xacc[3], .01f * xacc[3])); \
        *(f16x4*)(xb + wv * 512 + xwr) = xp;                                    \
    }                                                                           \
    __syncthreads();  /* x(t+1) ready */                                        \
} while (0)

    #pragma unroll 1
    for (int tt = 0; tt < NSTEP; tt += 2) {
        STEP(0, 16384, tt);
        STEP(16384, 0, tt + 1);
    }
#undef STEP
}

extern "C" void kernel_launch(void* const* d_in, const int* in_sizes, int n_in,
                              void* d_out, int out_size, void* d_ws, size_t ws_size,
                              hipStream_t stream) {
    const float* last_obs_rel = (const float*)d_in[1];
    const float* h0     = (const float*)d_in[2];
    const float* c0     = (const float*)d_in[3];
    const float* W_ih   = (const float*)d_in[4];
    const float* W_hh   = (const float*)d_in[5];
    const float* b_ih   = (const float*)d_in[6];
    const float* b_hh   = (const float*)d_in[7];
    const float* W_emb  = (const float*)d_in[8];
    const float* b_emb  = (const float*)d_in[9];
    const float* W_pos  = (const float*)d_in[10];
    const float* b_pos  = (const float*)d_in[11];
    const float* W_conf = (const float*)d_in[12];
    const float* b_conf = (const float*)d_in[13];
    float* out = (float*)d_out;

    const int batch = in_sizes[1] / 2;   // last_obs_rel is (B,2)
    const int grid  = (batch + MT - 1) / MT;
    mdlstm_kernel<<<grid, 512, 0, stream>>>(last_obs_rel, h0, c0, W_ih, W_hh,
                                            b_ih, b_hh, W_emb, b_emb, W_pos,
                                            b_pos, W_conf, b_conf, out, batch);
}